// Round 1
// baseline (150.750 us; speedup 1.0000x reference)
//
#include <hip/hip_runtime.h>
#include <hip/hip_bf16.h>
#include <math.h>

// Sizes (fixed by the reference problem)
#define BSZ 64
#define DV  1024
#define NQ  32
#define NS  1024
#define DD  128

#define ALPHA 0.5f

#define BG 4        // b-rows per block in multi kernel (d[c] reuse factor)
#define SC 128      // s-chunk staged in LDS
#define ROWB 272    // LDS row stride in bytes: 128 bf16 = 256B + 16B pad (16B-aligned, breaks bank conflicts)

typedef __attribute__((ext_vector_type(8))) short short8;   // 8 bf16 = 4 VGPRs (MFMA A/B frag)
typedef __attribute__((ext_vector_type(4))) float floatx4;  // MFMA C/D frag

// ---------------- pre-pass: fp32 -> bf16 for q_multi and d_multi ----------------
__global__ void cvt_bf16_kernel(const float* __restrict__ qm, const float* __restrict__ dm,
                                unsigned short* __restrict__ qb, unsigned short* __restrict__ db) {
    const int QG = (BSZ * NQ * DD) / 4;   // 65536 float4 groups
    const int DG = (BSZ * NS * DD) / 4;   // 2097152
    int idx = blockIdx.x * blockDim.x + threadIdx.x;
    int stride = gridDim.x * blockDim.x;
    for (int g = idx; g < QG + DG; g += stride) {
        float4 v;
        unsigned short* dst;
        if (g < QG) { v = ((const float4*)qm)[g]; dst = qb + g * 4; }
        else        { int h = g - QG; v = ((const float4*)dm)[h]; dst = db + (size_t)h * 4; }
        __hip_bfloat16 a = __float2bfloat16(v.x);
        __hip_bfloat16 b = __float2bfloat16(v.y);
        __hip_bfloat16 c = __float2bfloat16(v.z);
        __hip_bfloat16 d = __float2bfloat16(v.w);
        ushort4 u;
        u.x = *(unsigned short*)&a; u.y = *(unsigned short*)&b;
        u.z = *(unsigned short*)&c; u.w = *(unsigned short*)&d;
        *(ushort4*)dst = u;
    }
}

// ---------------- single-vector CE loss (fp32, tiny) ----------------
// scores[b][c] = q_single[b] . d_single[c]; loss = sum_b (logsumexp_c - scores[b][b])
__global__ void single_loss_kernel(const float* __restrict__ q, const float* __restrict__ d,
                                   float* __restrict__ out) {
    int b = blockIdx.x;          // 64 blocks, one per row
    int t = threadIdx.x;         // 256 threads
    int c = t >> 2, part = t & 3;
    const float4* qv = (const float4*)(q + b * DV);
    const float4* dv = (const float4*)(d + c * DV);
    float acc = 0.f;
    int k0 = part * 64;          // 256 float4 per row / 4 parts
#pragma unroll 8
    for (int k = k0; k < k0 + 64; ++k) {
        float4 a = qv[k], bb = dv[k];
        acc += a.x * bb.x + a.y * bb.y + a.z * bb.z + a.w * bb.w;
    }
    acc += __shfl_xor(acc, 1);
    acc += __shfl_xor(acc, 2);
    __shared__ float row[BSZ];
    if (part == 0) row[c] = acc;
    __syncthreads();
    if (t < BSZ) {               // lanes 0..63 of wave 0
        float v = row[t];
        float m = v;
#pragma unroll
        for (int o = 1; o < 64; o <<= 1) m = fmaxf(m, __shfl_xor(m, o));
        float e = expf(v - m);
#pragma unroll
        for (int o = 1; o < 64; o <<= 1) e += __shfl_xor(e, o);
        float lse = m + logf(e);
        if (t == 0) atomicAdd(out, ALPHA * (lse - row[b]));
    }
}

// ---------------- multi-vector late-interaction scores via MFMA ----------------
// block = (bg, c): computes scores[bg*4 .. bg*4+3][c]
// scores[b][c] = sum_n max_s ( Q[b,n,:] . D[c,s,:] )
__launch_bounds__(256, 2)
__global__ void multi_scores_kernel(const unsigned short* __restrict__ qb,
                                    const unsigned short* __restrict__ db,
                                    float* __restrict__ scores) {
    int bg = blockIdx.x;         // 0..15
    int c  = blockIdx.y;         // 0..63
    int t  = threadIdx.x;        // 256
    int w  = t >> 6;             // wave 0..3
    int l  = t & 63;
    int lane16 = l & 15;
    int quad   = (l >> 4) & 3;

    __shared__ __align__(16) unsigned char dch[SC * ROWB];   // 34816 B staged D chunk (bf16)
    __shared__ float smax[4][BG][NQ];                        // per-wave partial row-maxes

    // A fragments held in registers for the whole kernel:
    // af[bi][nt][ks] = Q[bg*4+bi][nt*16 + lane16][ks*32 + quad*8 .. +8]   (A[m=lane&15][k=quad*8+j])
    short8 af[BG][2][4];
#pragma unroll
    for (int bi = 0; bi < BG; ++bi)
#pragma unroll
        for (int nt = 0; nt < 2; ++nt)
#pragma unroll
            for (int ks = 0; ks < 4; ++ks)
                af[bi][nt][ks] = *(const short8*)(qb +
                    ((size_t)((bg * BG + bi) * NQ + nt * 16 + lane16) * DD + ks * 32 + quad * 8));

    float mx[BG][2][4];
#pragma unroll
    for (int bi = 0; bi < BG; ++bi)
#pragma unroll
        for (int nt = 0; nt < 2; ++nt)
#pragma unroll
            for (int r = 0; r < 4; ++r) mx[bi][nt][r] = -1e30f;

    const unsigned short* dbase = db + (size_t)c * NS * DD;

    for (int sc = 0; sc < NS / SC; ++sc) {
        __syncthreads();  // previous chunk's LDS reads done before overwrite
        // stage 128 s-rows x 128 bf16 (32 KB) -> LDS, row stride 272B
        {
            const uint4* src = (const uint4*)(dbase + (size_t)sc * SC * DD);  // 2048 uint4
#pragma unroll
            for (int p = 0; p < 8; ++p) {
                int f = t + p * 256;
                int row = f >> 4, col = f & 15;
                *(uint4*)(dch + row * ROWB + col * 16) = src[f];
            }
        }
        __syncthreads();
        // each wave: 2 s-tiles of 16; B[n=lane&15][k=quad*8+j] from LDS
#pragma unroll
        for (int sti = 0; sti < 2; ++sti) {
            int st = w + sti * 4;
            short8 bf[4];
#pragma unroll
            for (int ks = 0; ks < 4; ++ks)
                bf[ks] = *(const short8*)(dch + (st * 16 + lane16) * ROWB + ks * 64 + quad * 16);
            floatx4 acc[BG][2];
#pragma unroll
            for (int bi = 0; bi < BG; ++bi)
#pragma unroll
                for (int nt = 0; nt < 2; ++nt) acc[bi][nt] = (floatx4){0.f, 0.f, 0.f, 0.f};
#pragma unroll
            for (int ks = 0; ks < 4; ++ks)
#pragma unroll
                for (int bi = 0; bi < BG; ++bi)
#pragma unroll
                    for (int nt = 0; nt < 2; ++nt)
                        acc[bi][nt] = __builtin_amdgcn_mfma_f32_16x16x32_bf16(
                            af[bi][nt][ks], bf[ks], acc[bi][nt], 0, 0, 0);
            // C/D layout: col(s) = lane&15, row(n) = quad*4 + reg  -> max over s
#pragma unroll
            for (int bi = 0; bi < BG; ++bi)
#pragma unroll
                for (int nt = 0; nt < 2; ++nt)
#pragma unroll
                    for (int r = 0; r < 4; ++r)
                        mx[bi][nt][r] = fmaxf(mx[bi][nt][r], acc[bi][nt][r]);
        }
    }

    // max across the 16 lanes holding different s-columns
#pragma unroll
    for (int bi = 0; bi < BG; ++bi)
#pragma unroll
        for (int nt = 0; nt < 2; ++nt)
#pragma unroll
            for (int r = 0; r < 4; ++r) {
                float v = mx[bi][nt][r];
                v = fmaxf(v, __shfl_xor(v, 1));
                v = fmaxf(v, __shfl_xor(v, 2));
                v = fmaxf(v, __shfl_xor(v, 4));
                v = fmaxf(v, __shfl_xor(v, 8));
                mx[bi][nt][r] = v;
            }
    __syncthreads();
    if (lane16 == 0) {
#pragma unroll
        for (int bi = 0; bi < BG; ++bi)
#pragma unroll
            for (int nt = 0; nt < 2; ++nt)
#pragma unroll
                for (int r = 0; r < 4; ++r)
                    smax[w][bi][nt * 16 + quad * 4 + r] = mx[bi][nt][r];
    }
    __syncthreads();
    // combine waves, then sum over the 32 query tokens
    if (t < BG * NQ) {
        int bi = t >> 5, n = t & 31;
        float v = fmaxf(fmaxf(smax[0][bi][n], smax[1][bi][n]),
                        fmaxf(smax[2][bi][n], smax[3][bi][n]));
#pragma unroll
        for (int o = 1; o < 32; o <<= 1) v += __shfl_xor(v, o);
        if (n == 0) scores[(bg * BG + bi) * BSZ + c] = v;
    }
}

// ---------------- finisher: softplus margin loss from scores ----------------
__global__ void finish_kernel(const float* __restrict__ scores, float* __restrict__ out) {
    int t = threadIdx.x;  // 64
    float pos = scores[t * BSZ + t];
    float neg = -1e30f;
    for (int cc = 0; cc < BSZ; ++cc)
        if (cc != t) neg = fmaxf(neg, scores[t * BSZ + cc]);
    float x = neg - pos;
    float sp = fmaxf(x, 0.f) + log1pf(expf(-fabsf(x)));   // stable softplus
#pragma unroll
    for (int o = 1; o < 64; o <<= 1) sp += __shfl_xor(sp, o);
    if (t == 0) atomicAdd(out, (1.0f - ALPHA) * sp * (1.0f / BSZ));
}

// ---------------- launch ----------------
extern "C" void kernel_launch(void* const* d_in, const int* in_sizes, int n_in,
                              void* d_out, int out_size, void* d_ws, size_t ws_size,
                              hipStream_t stream) {
    const float* q_single = (const float*)d_in[0];
    const float* d_single = (const float*)d_in[1];
    const float* q_multi  = (const float*)d_in[2];
    const float* d_multi  = (const float*)d_in[3];
    float* out = (float*)d_out;

    // workspace layout: qb (512 KB) | db (16 MB) | scores (16 KB)  => needs ~17.3 MB
    unsigned short* qb = (unsigned short*)d_ws;
    unsigned short* db = (unsigned short*)((char*)d_ws + 524288);
    float* scores      = (float*)((char*)d_ws + 524288 + 16777216);

    hipMemsetAsync(d_out, 0, sizeof(float), stream);
    cvt_bf16_kernel<<<1024, 256, 0, stream>>>(q_multi, d_multi, qb, db);
    single_loss_kernel<<<BSZ, 256, 0, stream>>>(q_single, d_single, out);
    multi_scores_kernel<<<dim3(16, 64), 256, 0, stream>>>(qb, db, scores);
    finish_kernel<<<1, 64, 0, stream>>>(scores, out);
}